// Round 8
// baseline (1909.546 us; speedup 1.0000x reference)
//
#include <hip/hip_runtime.h>
#include <hip/hip_bf16.h>

#define TB 512
#define NB 64
#define HID 300
#define HHALF 150
#define G4 600
#define KP 320
#define MTOT (NB*TB)
#define NTAG 16
#define NEGV -10000.0f

using short8 = __attribute__((ext_vector_type(8))) short;
using f32x4  = __attribute__((ext_vector_type(4))) float;
using u32x8  = __attribute__((ext_vector_type(8))) unsigned;
using u32x4  = __attribute__((ext_vector_type(4))) unsigned;
using half2v = __attribute__((ext_vector_type(2))) _Float16;

__device__ __forceinline__ unsigned short f2bf(float f){
  union { float f; unsigned u; } v; v.f = f;
  unsigned r = v.u + 0x7FFFu + ((v.u >> 16) & 1u);
  return (unsigned short)(r >> 16);
}
__device__ __forceinline__ float fsig(float x){ return __fdividef(1.f, 1.f + __expf(-x)); }
__device__ __forceinline__ float ftanh(float x){ return 1.f - __fdividef(2.f, __expf(2.f*x) + 1.f); }

__device__ __forceinline__ unsigned pkh(float a, float b){
  _Float16 ha = (_Float16)a, hb = (_Float16)b;
  unsigned short ua, ub;
  __builtin_memcpy(&ua, &ha, 2); __builtin_memcpy(&ub, &hb, 2);
  return (unsigned)ua | ((unsigned)ub << 16);
}
__device__ __forceinline__ float dot2(unsigned w, unsigned h, float acc){
  half2v wv, hv;
  __builtin_memcpy(&wv, &w, 4); __builtin_memcpy(&hv, &h, 4);
  return __builtin_amdgcn_fdot2(wv, hv, acc, false);
}

// raw workgroup barrier: order LDS only, leave vmcnt in flight
__device__ __forceinline__ void bar_lds(){
  asm volatile("s_waitcnt lgkmcnt(0)" ::: "memory");
  __builtin_amdgcn_s_barrier();
  asm volatile("" ::: "memory");
}

// ---- staging / conversion kernels ----
__global__ void k_gather_embed(const int* __restrict__ x, const float* __restrict__ emb,
                               unsigned short* __restrict__ Abf){
  long long total = (long long)MTOT * KP;
  for (long long idx = (long long)blockIdx.x*blockDim.x + threadIdx.x; idx < total;
       idx += (long long)gridDim.x*blockDim.x){
    int m = (int)(idx / KP), k = (int)(idx % KP);
    float v = 0.f;
    if (k < HID) v = emb[(long long)x[m]*HID + k];
    Abf[idx] = f2bf(v);
  }
}

__global__ void k_cvt_h(const float* __restrict__ h, unsigned short* __restrict__ Abf){
  long long total = (long long)MTOT * KP;
  for (long long idx = (long long)blockIdx.x*blockDim.x + threadIdx.x; idx < total;
       idx += (long long)gridDim.x*blockDim.x){
    int m = (int)(idx / KP), k = (int)(idx % KP);
    Abf[idx] = f2bf(k < HID ? h[(long long)m*HID + k] : 0.f);
  }
}

__global__ void k_cvt_w(const float* __restrict__ Wih, const float* __restrict__ bih,
                        const float* __restrict__ bhh,
                        unsigned short* __restrict__ Wbf, float* __restrict__ bsum){
  int idx = blockIdx.x*blockDim.x + threadIdx.x;
  if (idx >= 1216*KP) return;
  int n = idx / KP, k = idx % KP;
  float v = (n < 1200 && k < HID) ? Wih[(long long)n*HID + k] : 0.f;
  Wbf[idx] = f2bf(v);
  if (k == 0) bsum[n] = (n < 1200) ? (bih[n] + bhh[n]) : 0.f;
}

// ---- bf16 MFMA projection GEMM: pre[dir][m][j] = A(m,k) @ W(n,k)^T + bsum ----
__global__ __launch_bounds__(256) void k_proj(const unsigned short* __restrict__ A,
                                              const unsigned short* __restrict__ Wb,
                                              const float* __restrict__ bsum,
                                              float* __restrict__ pre){
  int m0 = blockIdx.x * 128;
  int n0 = blockIdx.y * 64;
  int wid = threadIdx.x >> 6, lane = threadIdx.x & 63;
  int la = lane & 15, lk = lane >> 4;
  int mw = m0 + wid*32;
  f32x4 acc[2][4];
  #pragma unroll
  for (int i=0;i<2;i++){
    #pragma unroll
    for (int j=0;j<4;j++){ acc[i][j][0]=0.f; acc[i][j][1]=0.f; acc[i][j][2]=0.f; acc[i][j][3]=0.f; }
  }
  const unsigned short* Ap = A  + (long long)(mw + la)*KP + lk*8;
  const unsigned short* Bp = Wb + (long long)(n0 + la)*KP + lk*8;
  #pragma unroll 2
  for (int kk=0; kk<KP; kk+=32){
    short8 a0 = *(const short8*)(Ap + kk);
    short8 a1 = *(const short8*)(Ap + 16*KP + kk);
    short8 b0 = *(const short8*)(Bp + kk);
    short8 b1 = *(const short8*)(Bp + 16*KP + kk);
    short8 b2 = *(const short8*)(Bp + 32*KP + kk);
    short8 b3 = *(const short8*)(Bp + 48*KP + kk);
    acc[0][0] = __builtin_amdgcn_mfma_f32_16x16x32_bf16(a0,b0,acc[0][0],0,0,0);
    acc[0][1] = __builtin_amdgcn_mfma_f32_16x16x32_bf16(a0,b1,acc[0][1],0,0,0);
    acc[0][2] = __builtin_amdgcn_mfma_f32_16x16x32_bf16(a0,b2,acc[0][2],0,0,0);
    acc[0][3] = __builtin_amdgcn_mfma_f32_16x16x32_bf16(a0,b3,acc[0][3],0,0,0);
    acc[1][0] = __builtin_amdgcn_mfma_f32_16x16x32_bf16(a1,b0,acc[1][0],0,0,0);
    acc[1][1] = __builtin_amdgcn_mfma_f32_16x16x32_bf16(a1,b1,acc[1][1],0,0,0);
    acc[1][2] = __builtin_amdgcn_mfma_f32_16x16x32_bf16(a1,b2,acc[1][2],0,0,0);
    acc[1][3] = __builtin_amdgcn_mfma_f32_16x16x32_bf16(a1,b3,acc[1][3],0,0,0);
  }
  #pragma unroll
  for (int ms=0; ms<2; ms++){
    #pragma unroll
    for (int ns=0; ns<4; ns++){
      int n = n0 + ns*16 + la;
      if (n < 1200){
        int dir = (n >= 600) ? 1 : 0;
        int j = n - dir*600;
        float bs = bsum[n];
        #pragma unroll
        for (int r=0;r<4;r++){
          int row = mw + ms*16 + lk*4 + r;
          pre[((long long)dir*MTOT + row)*G4 + j] = acc[ms][ns][r] + bs;
        }
      }
    }
  }
}

// ---- LSTM recurrence ----
// 320 threads (5 waves). Thread pair (2m, 2m+1) owns cell m: even lane computes
// gate rows (i,f) = (m, m+150), odd lane rows (g,o) = (m+300, m+450). All weights
// register-resident as packed-f16 named ext-vectors (R6/R7-proven). Activation is
// lane-local after one __shfl_xor(.,1) pair exchange: no g_lds round trip, and h
// double-buffered in LDS f16 => ONE barrier per step (was 2 + LDS gate traffic).
#define MK8(P,B) (u32x8){ pkh(P[(B)],P[(B)+1]), pkh(P[(B)+2],P[(B)+3]), \
  pkh(P[(B)+4],P[(B)+5]), pkh(P[(B)+6],P[(B)+7]), pkh(P[(B)+8],P[(B)+9]), \
  pkh(P[(B)+10],P[(B)+11]), pkh(P[(B)+12],P[(B)+13]), pkh(P[(B)+14],P[(B)+15]) }
#define MK4T(P) (u32x4){ pkh(P[144],P[145]), pkh(P[146],P[147]), pkh(P[148],P[149]), 0u }
#define DOTQ(hq, W0, E0, W1, E1) { u32x4 hv = hp[(hq)]; \
  a0 = dot2(W0[(E0)+0], hv.x, a0); b0 = dot2(W0[(E0)+1], hv.y, b0); \
  a0 = dot2(W0[(E0)+2], hv.z, a0); b0 = dot2(W0[(E0)+3], hv.w, b0); \
  a1 = dot2(W1[(E1)+0], hv.x, a1); b1 = dot2(W1[(E1)+1], hv.y, b1); \
  a1 = dot2(W1[(E1)+2], hv.z, a1); b1 = dot2(W1[(E1)+3], hv.w, b1); }

__global__ __launch_bounds__(320, 1) void k_rec(const float* __restrict__ pre,
                                                const float* __restrict__ Whh,
                                                const int* __restrict__ x,
                                                float* __restrict__ hout){
  int dir = blockIdx.x >> 6;
  int b   = blockIdx.x & 63;
  int tid = threadIdx.x;
  int act = (tid < 300);
  int m   = act ? (tid >> 1) : 0;
  int sub = tid & 1;
  __shared__ __align__(16) unsigned short h16[2][152];
  __shared__ int x_lds[TB];
  // gate rows this lane owns: even: (m, m+150)=(i,f); odd: (m+300, m+450)=(g,o)
  int rA = m + sub*300;
  int rB = m + 150 + sub*300;
  const float* wr0 = Whh + (long long)(dir*G4 + rA)*HHALF;
  const float* wr1 = Whh + (long long)(dir*G4 + rB)*HHALF;
  u32x8 w0_0,w0_1,w0_2,w0_3,w0_4,w0_5,w0_6,w0_7,w0_8;
  u32x8 w1_0,w1_1,w1_2,w1_3,w1_4,w1_5,w1_6,w1_7,w1_8;
  u32x4 w0_9, w1_9;
  if (act){
    w0_0=MK8(wr0,0);   w0_1=MK8(wr0,16);  w0_2=MK8(wr0,32);  w0_3=MK8(wr0,48);
    w0_4=MK8(wr0,64);  w0_5=MK8(wr0,80);  w0_6=MK8(wr0,96);  w0_7=MK8(wr0,112);
    w0_8=MK8(wr0,128); w0_9=MK4T(wr0);
    w1_0=MK8(wr1,0);   w1_1=MK8(wr1,16);  w1_2=MK8(wr1,32);  w1_3=MK8(wr1,48);
    w1_4=MK8(wr1,64);  w1_5=MK8(wr1,80);  w1_6=MK8(wr1,96);  w1_7=MK8(wr1,112);
    w1_8=MK8(wr1,128); w1_9=MK4T(wr1);
  } else {
    w0_0=(u32x8)(0u);w0_1=(u32x8)(0u);w0_2=(u32x8)(0u);w0_3=(u32x8)(0u);
    w0_4=(u32x8)(0u);w0_5=(u32x8)(0u);w0_6=(u32x8)(0u);w0_7=(u32x8)(0u);
    w0_8=(u32x8)(0u);w0_9=(u32x4)(0u);
    w1_0=(u32x8)(0u);w1_1=(u32x8)(0u);w1_2=(u32x8)(0u);w1_3=(u32x8)(0u);
    w1_4=(u32x8)(0u);w1_5=(u32x8)(0u);w1_6=(u32x8)(0u);w1_7=(u32x8)(0u);
    w1_8=(u32x8)(0u);w1_9=(u32x4)(0u);
  }
  if (tid < 152){ h16[0][tid] = 0; h16[1][tid] = 0; }
  for (int q = tid; q < TB; q += 320) x_lds[q] = x[b*TB + q];
  float c = 0.f, hreg = 0.f;
  const float* preB = pre + ((long long)dir*MTOT + (long long)b*TB)*G4;
  float* hb = hout + (long long)b*TB*HID + dir*HHALF + m;
  int t0 = dir ? (TB-1) : 0;
  float pv0_c = preB[(long long)t0*G4 + rA];
  float pv1_c = preB[(long long)t0*G4 + rB];
  bar_lds();
  #pragma unroll 1
  for (int s=0; s<TB; s++){
    int t = dir ? (TB-1-s) : s;
    int sn = (s+1 < TB) ? (s+1) : s;
    int tn = dir ? (TB-1-sn) : sn;
    float pv0_n = preB[(long long)tn*G4 + rA];
    float pv1_n = preB[(long long)tn*G4 + rB];
    int xv = x_lds[t];
    if (xv > 0){
      const u32x4* hp = (const u32x4*)h16[s & 1];
      float a0=0.f, b0=0.f, a1=0.f, b1=0.f;
      DOTQ(0,  w0_0,0, w1_0,0) DOTQ(1,  w0_0,4, w1_0,4)
      DOTQ(2,  w0_1,0, w1_1,0) DOTQ(3,  w0_1,4, w1_1,4)
      DOTQ(4,  w0_2,0, w1_2,0) DOTQ(5,  w0_2,4, w1_2,4)
      DOTQ(6,  w0_3,0, w1_3,0) DOTQ(7,  w0_3,4, w1_3,4)
      DOTQ(8,  w0_4,0, w1_4,0) DOTQ(9,  w0_4,4, w1_4,4)
      DOTQ(10, w0_5,0, w1_5,0) DOTQ(11, w0_5,4, w1_5,4)
      DOTQ(12, w0_6,0, w1_6,0) DOTQ(13, w0_6,4, w1_6,4)
      DOTQ(14, w0_7,0, w1_7,0) DOTQ(15, w0_7,4, w1_7,4)
      DOTQ(16, w0_8,0, w1_8,0) DOTQ(17, w0_8,4, w1_8,4)
      DOTQ(18, w0_9,0, w1_9,0)
      float gA = pv0_c + (a0 + b0);      // even: i_pre ; odd: g_pre
      float gB = pv1_c + (a1 + b1);      // even: f_pre ; odd: o_pre
      float pA = __shfl_xor(gA, 1);
      float pB = __shfl_xor(gB, 1);
      float ig = sub ? pA : gA;
      float fg = sub ? pB : gB;
      float gg = sub ? gA : pA;
      float og = sub ? gB : pB;
      float cn = fsig(fg)*c + fsig(ig)*ftanh(gg);
      float hn = fsig(og)*ftanh(cn);
      c = cn; hreg = hn;
    }
    if (act & (sub == 0)){
      _Float16 hh = (_Float16)hreg;
      unsigned short hu; __builtin_memcpy(&hu, &hh, 2);
      h16[(s+1) & 1][m] = hu;
      hb[(long long)t*HID] = hreg;
    }
    bar_lds();
    pv0_c = pv0_n; pv1_c = pv1_n;
  }
}

// ---- emissions: (h2 @ Wout.T + bout) * mask ----
__global__ __launch_bounds__(256) void k_emis(const float* __restrict__ h2,
                                              const float* __restrict__ Wout,
                                              const float* __restrict__ bout,
                                              const int* __restrict__ x,
                                              float* __restrict__ emis){
  int m = blockIdx.x*16 + (threadIdx.x >> 4);
  int n = threadIdx.x & 15;
  const float* hr = h2 + (long long)m*HID;
  const float* wr = Wout + n*HID;
  float acc = 0.f;
  #pragma unroll 4
  for (int k=0;k<HID;k++) acc += hr[k]*wr[k];
  float mm = (x[m] > 0) ? 1.f : 0.f;
  emis[(long long)m*NTAG + n] = (acc + bout[n]) * mm;
}

// ---- CRF partition: one wave per batch, alpha fully in registers ----
__global__ __launch_bounds__(64) void k_crf_part(const float* __restrict__ emis,
                                                 const float* __restrict__ trans,
                                                 const int* __restrict__ x,
                                                 float* __restrict__ out){
  int b = blockIdx.x;
  int lane = threadIdx.x;
  int i = lane & 15, q = lane >> 4;
  float t0 = trans[i*16 + q*4 + 0];
  float t1 = trans[i*16 + q*4 + 1];
  float t2 = trans[i*16 + q*4 + 2];
  float t3 = trans[i*16 + q*4 + 3];
  float al = (i == 14) ? 0.f : NEGV;
  const float* eb = emis + (long long)b*TB*NTAG + i;
  const int* xb = x + b*TB;
  float ht_n = eb[0];
  int   xv_n = xb[0];
  #pragma unroll 1
  for (int t=0; t<TB; t++){
    float ht = ht_n; int xv = xv_n;
    if (t+1 < TB){ ht_n = eb[(t+1)*NTAG]; xv_n = xb[t+1]; }
    if (xv > 0){
      float a0 = __shfl(al, q*4+0);
      float a1 = __shfl(al, q*4+1);
      float a2 = __shfl(al, q*4+2);
      float a3 = __shfl(al, q*4+3);
      float v0 = a0+t0, v1 = a1+t1, v2 = a2+t2, v3 = a3+t3;
      float mx = fmaxf(fmaxf(v0,v1), fmaxf(v2,v3));
      mx = fmaxf(mx, __shfl_xor(mx, 16));
      mx = fmaxf(mx, __shfl_xor(mx, 32));
      float sm = __expf(v0-mx) + __expf(v1-mx) + __expf(v2-mx) + __expf(v3-mx);
      sm += __shfl_xor(sm, 16);
      sm += __shfl_xor(sm, 32);
      al = mx + __logf(sm) + ht;
    }
  }
  float av = (lane < 16) ? (al + trans[15*16 + lane]) : -3.0e38f;
  float mx = av;
  mx = fmaxf(mx, __shfl_xor(mx, 1));
  mx = fmaxf(mx, __shfl_xor(mx, 2));
  mx = fmaxf(mx, __shfl_xor(mx, 4));
  mx = fmaxf(mx, __shfl_xor(mx, 8));
  float sm = (lane < 16) ? __expf(av - mx) : 0.f;
  sm += __shfl_xor(sm, 1);
  sm += __shfl_xor(sm, 2);
  sm += __shfl_xor(sm, 4);
  sm += __shfl_xor(sm, 8);
  if (lane == 0) out[b] = mx + __logf(sm);
}

// ---- CRF gold score: out[b] -= score ----
__global__ __launch_bounds__(64) void k_crf_score(const float* __restrict__ emis,
                                                  const float* __restrict__ trans,
                                                  const int* __restrict__ x,
                                                  const int* __restrict__ y,
                                                  float* __restrict__ out){
  int b = blockIdx.x;
  int lane = threadIdx.x;
  float part = 0.f; int cnt = 0;
  for (int t = lane; t < TB; t += 64){
    if (x[b*TB + t] > 0){
      int yt = y[b*TB + t];
      int prev = (t == 0) ? 14 : y[b*TB + t - 1];
      part += emis[((long long)b*TB + t)*NTAG + yt] + trans[yt*16 + prev];
      cnt++;
    }
  }
  #pragma unroll
  for (int d=1; d<64; d<<=1){ part += __shfl_xor(part, d); cnt += __shfl_xor(cnt, d); }
  if (lane == 0){
    int last = (cnt == 0) ? 14 : y[b*TB + cnt - 1];
    out[b] -= (part + trans[15*16 + last]);
  }
}

extern "C" void kernel_launch(void* const* d_in, const int* in_sizes, int n_in,
                              void* d_out, int out_size, void* d_ws, size_t ws_size,
                              hipStream_t stream){
  const int*   x     = (const int*)d_in[0];
  const int*   y     = (const int*)d_in[1];
  const float* emb   = (const float*)d_in[2];
  const float* Wih0  = (const float*)d_in[3];
  const float* Whh0  = (const float*)d_in[4];
  const float* bih0  = (const float*)d_in[5];
  const float* bhh0  = (const float*)d_in[6];
  const float* Wih1  = (const float*)d_in[7];
  const float* Whh1  = (const float*)d_in[8];
  const float* bih1  = (const float*)d_in[9];
  const float* bhh1  = (const float*)d_in[10];
  const float* Wout  = (const float*)d_in[11];
  const float* bout  = (const float*)d_in[12];
  const float* trans = (const float*)d_in[13];
  float* out = (float*)d_out;

  char* ws = (char*)d_ws;
  size_t off = 0;
  auto alloc = [&](size_t n){ char* p = ws + off; off = (off + n + 255) & ~(size_t)255; return p; };
  unsigned short* Abf  = (unsigned short*)alloc((size_t)MTOT*KP*2);
  unsigned short* Wbf0 = (unsigned short*)alloc((size_t)1216*KP*2);
  unsigned short* Wbf1 = (unsigned short*)alloc((size_t)1216*KP*2);
  float* bsum0 = (float*)alloc(1216*4);
  float* bsum1 = (float*)alloc(1216*4);
  float* pre   = (float*)alloc((size_t)2*MTOT*G4*4);
  float* h1    = (float*)alloc((size_t)MTOT*HID*4);
  float* h2    = (float*)alloc((size_t)MTOT*HID*4);
  float* emis  = (float*)alloc((size_t)MTOT*NTAG*4);

  hipLaunchKernelGGL(k_cvt_w, dim3(1520), dim3(256), 0, stream, Wih0, bih0, bhh0, Wbf0, bsum0);
  hipLaunchKernelGGL(k_cvt_w, dim3(1520), dim3(256), 0, stream, Wih1, bih1, bhh1, Wbf1, bsum1);
  hipLaunchKernelGGL(k_gather_embed, dim3(4096), dim3(256), 0, stream, x, emb, Abf);
  hipLaunchKernelGGL(k_proj, dim3(256,19), dim3(256), 0, stream, Abf, Wbf0, bsum0, pre);
  hipLaunchKernelGGL(k_rec, dim3(128), dim3(320), 0, stream, pre, Whh0, x, h1);
  hipLaunchKernelGGL(k_cvt_h, dim3(4096), dim3(256), 0, stream, h1, Abf);
  hipLaunchKernelGGL(k_proj, dim3(256,19), dim3(256), 0, stream, Abf, Wbf1, bsum1, pre);
  hipLaunchKernelGGL(k_rec, dim3(128), dim3(320), 0, stream, pre, Whh1, x, h2);
  hipLaunchKernelGGL(k_emis, dim3(2048), dim3(256), 0, stream, h2, Wout, bout, x, emis);
  hipLaunchKernelGGL(k_crf_part, dim3(64), dim3(64), 0, stream, emis, trans, x, out);
  hipLaunchKernelGGL(k_crf_score, dim3(64), dim3(64), 0, stream, emis, trans, x, y, out);
}

// Round 9
// 1736.855 us; speedup vs baseline: 1.0994x; 1.0994x over previous
//
#include <hip/hip_runtime.h>
#include <hip/hip_bf16.h>

#define TB 512
#define NB 64
#define HID 300
#define HHALF 150
#define G4 600
#define KP 320
#define MTOT (NB*TB)
#define NTAG 16
#define NEGV -10000.0f

using short8 = __attribute__((ext_vector_type(8))) short;
using f32x4  = __attribute__((ext_vector_type(4))) float;
using u32x8  = __attribute__((ext_vector_type(8))) unsigned;
using u32x4  = __attribute__((ext_vector_type(4))) unsigned;
using half2v = __attribute__((ext_vector_type(2))) _Float16;

__device__ __forceinline__ unsigned short f2bf(float f){
  union { float f; unsigned u; } v; v.f = f;
  unsigned r = v.u + 0x7FFFu + ((v.u >> 16) & 1u);
  return (unsigned short)(r >> 16);
}
__device__ __forceinline__ float fsig(float x){ return __fdividef(1.f, 1.f + __expf(-x)); }
__device__ __forceinline__ float ftanh(float x){ return 1.f - __fdividef(2.f, __expf(2.f*x) + 1.f); }

__device__ __forceinline__ unsigned pkh(float a, float b){
  _Float16 ha = (_Float16)a, hb = (_Float16)b;
  unsigned short ua, ub;
  __builtin_memcpy(&ua, &ha, 2); __builtin_memcpy(&ub, &hb, 2);
  return (unsigned)ua | ((unsigned)ub << 16);
}
__device__ __forceinline__ float dot2(unsigned w, unsigned h, float acc){
  half2v wv, hv;
  __builtin_memcpy(&wv, &w, 4); __builtin_memcpy(&hv, &h, 4);
  return __builtin_amdgcn_fdot2(wv, hv, acc, false);
}

// raw workgroup barrier: order LDS only, leave vmcnt in flight
__device__ __forceinline__ void bar_lds(){
  asm volatile("s_waitcnt lgkmcnt(0)" ::: "memory");
  __builtin_amdgcn_s_barrier();
  asm volatile("" ::: "memory");
}

// ---- staging / conversion kernels ----
__global__ void k_gather_embed(const int* __restrict__ x, const float* __restrict__ emb,
                               unsigned short* __restrict__ Abf){
  long long total = (long long)MTOT * KP;
  for (long long idx = (long long)blockIdx.x*blockDim.x + threadIdx.x; idx < total;
       idx += (long long)gridDim.x*blockDim.x){
    int m = (int)(idx / KP), k = (int)(idx % KP);
    float v = 0.f;
    if (k < HID) v = emb[(long long)x[m]*HID + k];
    Abf[idx] = f2bf(v);
  }
}

__global__ void k_cvt_h(const float* __restrict__ h, unsigned short* __restrict__ Abf){
  long long total = (long long)MTOT * KP;
  for (long long idx = (long long)blockIdx.x*blockDim.x + threadIdx.x; idx < total;
       idx += (long long)gridDim.x*blockDim.x){
    int m = (int)(idx / KP), k = (int)(idx % KP);
    Abf[idx] = f2bf(k < HID ? h[(long long)m*HID + k] : 0.f);
  }
}

__global__ void k_cvt_w(const float* __restrict__ Wih, const float* __restrict__ bih,
                        const float* __restrict__ bhh,
                        unsigned short* __restrict__ Wbf, float* __restrict__ bsum){
  int idx = blockIdx.x*blockDim.x + threadIdx.x;
  if (idx >= 1216*KP) return;
  int n = idx / KP, k = idx % KP;
  float v = (n < 1200 && k < HID) ? Wih[(long long)n*HID + k] : 0.f;
  Wbf[idx] = f2bf(v);
  if (k == 0) bsum[n] = (n < 1200) ? (bih[n] + bhh[n]) : 0.f;
}

// Wout (16x300) -> padded bf16 panel (64x320) + bias
__global__ void k_cvt_wo(const float* __restrict__ Wout, const float* __restrict__ bout,
                         unsigned short* __restrict__ Wobf, float* __restrict__ bsumo){
  int idx = blockIdx.x*blockDim.x + threadIdx.x;
  if (idx >= 64*KP) return;
  int n = idx / KP, k = idx % KP;
  float v = (n < NTAG && k < HID) ? Wout[n*HID + k] : 0.f;
  Wobf[idx] = f2bf(v);
  if (k == 0) bsumo[n] = (n < NTAG) ? bout[n] : 0.f;
}

// ---- bf16 MFMA projection GEMM: pre[dir][m][j] = A(m,k) @ W(n,k)^T + bsum ----
__global__ __launch_bounds__(256) void k_proj(const unsigned short* __restrict__ A,
                                              const unsigned short* __restrict__ Wb,
                                              const float* __restrict__ bsum,
                                              float* __restrict__ pre){
  int m0 = blockIdx.x * 128;
  int n0 = blockIdx.y * 64;
  int wid = threadIdx.x >> 6, lane = threadIdx.x & 63;
  int la = lane & 15, lk = lane >> 4;
  int mw = m0 + wid*32;
  f32x4 acc[2][4];
  #pragma unroll
  for (int i=0;i<2;i++){
    #pragma unroll
    for (int j=0;j<4;j++){ acc[i][j][0]=0.f; acc[i][j][1]=0.f; acc[i][j][2]=0.f; acc[i][j][3]=0.f; }
  }
  const unsigned short* Ap = A  + (long long)(mw + la)*KP + lk*8;
  const unsigned short* Bp = Wb + (long long)(n0 + la)*KP + lk*8;
  #pragma unroll 2
  for (int kk=0; kk<KP; kk+=32){
    short8 a0 = *(const short8*)(Ap + kk);
    short8 a1 = *(const short8*)(Ap + 16*KP + kk);
    short8 b0 = *(const short8*)(Bp + kk);
    short8 b1 = *(const short8*)(Bp + 16*KP + kk);
    short8 b2 = *(const short8*)(Bp + 32*KP + kk);
    short8 b3 = *(const short8*)(Bp + 48*KP + kk);
    acc[0][0] = __builtin_amdgcn_mfma_f32_16x16x32_bf16(a0,b0,acc[0][0],0,0,0);
    acc[0][1] = __builtin_amdgcn_mfma_f32_16x16x32_bf16(a0,b1,acc[0][1],0,0,0);
    acc[0][2] = __builtin_amdgcn_mfma_f32_16x16x32_bf16(a0,b2,acc[0][2],0,0,0);
    acc[0][3] = __builtin_amdgcn_mfma_f32_16x16x32_bf16(a0,b3,acc[0][3],0,0,0);
    acc[1][0] = __builtin_amdgcn_mfma_f32_16x16x32_bf16(a1,b0,acc[1][0],0,0,0);
    acc[1][1] = __builtin_amdgcn_mfma_f32_16x16x32_bf16(a1,b1,acc[1][1],0,0,0);
    acc[1][2] = __builtin_amdgcn_mfma_f32_16x16x32_bf16(a1,b2,acc[1][2],0,0,0);
    acc[1][3] = __builtin_amdgcn_mfma_f32_16x16x32_bf16(a1,b3,acc[1][3],0,0,0);
  }
  #pragma unroll
  for (int ms=0; ms<2; ms++){
    #pragma unroll
    for (int ns=0; ns<4; ns++){
      int n = n0 + ns*16 + la;
      if (n < 1200){
        int dir = (n >= 600) ? 1 : 0;
        int j = n - dir*600;
        float bs = bsum[n];
        #pragma unroll
        for (int r=0;r<4;r++){
          int row = mw + ms*16 + lk*4 + r;
          pre[((long long)dir*MTOT + row)*G4 + j] = acc[ms][ns][r] + bs;
        }
      }
    }
  }
}

// ---- LSTM recurrence (R7 structure, proven 561 us) ----
// 320 threads (5 waves). Thread j<300 owns gate rows j and j+300; weights
// register-resident as packed-f16 named ext-vectors. h broadcast via LDS f16:
// 19 uniform ds_read_b128 per thread per step. dot2 consumes packed pairs.
#define MK8(P,B) (u32x8){ pkh(P[(B)],P[(B)+1]), pkh(P[(B)+2],P[(B)+3]), \
  pkh(P[(B)+4],P[(B)+5]), pkh(P[(B)+6],P[(B)+7]), pkh(P[(B)+8],P[(B)+9]), \
  pkh(P[(B)+10],P[(B)+11]), pkh(P[(B)+12],P[(B)+13]), pkh(P[(B)+14],P[(B)+15]) }
#define MK4T(P) (u32x4){ pkh(P[144],P[145]), pkh(P[146],P[147]), pkh(P[148],P[149]), 0u }
#define DOTQ(hq, W0, E0, W1, E1) { u32x4 hv = hp[(hq)]; \
  a0 = dot2(W0[(E0)+0], hv.x, a0); b0 = dot2(W0[(E0)+1], hv.y, b0); \
  a0 = dot2(W0[(E0)+2], hv.z, a0); b0 = dot2(W0[(E0)+3], hv.w, b0); \
  a1 = dot2(W1[(E1)+0], hv.x, a1); b1 = dot2(W1[(E1)+1], hv.y, b1); \
  a1 = dot2(W1[(E1)+2], hv.z, a1); b1 = dot2(W1[(E1)+3], hv.w, b1); }

__global__ __launch_bounds__(320, 1) void k_rec(const float* __restrict__ pre,
                                                const float* __restrict__ Whh,
                                                const int* __restrict__ x,
                                                float* __restrict__ hout){
  int dir = blockIdx.x >> 6;
  int b   = blockIdx.x & 63;
  int tid = threadIdx.x;
  __shared__ __align__(16) unsigned short h16[152];
  __shared__ float g_lds[G4];
  __shared__ int   x_lds[TB];
  const float* wr0 = Whh + (long long)(dir*G4 + tid)*HHALF;
  const float* wr1 = wr0 + 300*HHALF;
  u32x8 w0_0,w0_1,w0_2,w0_3,w0_4,w0_5,w0_6,w0_7,w0_8;
  u32x8 w1_0,w1_1,w1_2,w1_3,w1_4,w1_5,w1_6,w1_7,w1_8;
  u32x4 w0_9, w1_9;
  if (tid < 300){
    w0_0=MK8(wr0,0);   w0_1=MK8(wr0,16);  w0_2=MK8(wr0,32);  w0_3=MK8(wr0,48);
    w0_4=MK8(wr0,64);  w0_5=MK8(wr0,80);  w0_6=MK8(wr0,96);  w0_7=MK8(wr0,112);
    w0_8=MK8(wr0,128); w0_9=MK4T(wr0);
    w1_0=MK8(wr1,0);   w1_1=MK8(wr1,16);  w1_2=MK8(wr1,32);  w1_3=MK8(wr1,48);
    w1_4=MK8(wr1,64);  w1_5=MK8(wr1,80);  w1_6=MK8(wr1,96);  w1_7=MK8(wr1,112);
    w1_8=MK8(wr1,128); w1_9=MK4T(wr1);
  } else {
    w0_0=(u32x8)(0u);w0_1=(u32x8)(0u);w0_2=(u32x8)(0u);w0_3=(u32x8)(0u);
    w0_4=(u32x8)(0u);w0_5=(u32x8)(0u);w0_6=(u32x8)(0u);w0_7=(u32x8)(0u);
    w0_8=(u32x8)(0u);w0_9=(u32x4)(0u);
    w1_0=(u32x8)(0u);w1_1=(u32x8)(0u);w1_2=(u32x8)(0u);w1_3=(u32x8)(0u);
    w1_4=(u32x8)(0u);w1_5=(u32x8)(0u);w1_6=(u32x8)(0u);w1_7=(u32x8)(0u);
    w1_8=(u32x8)(0u);w1_9=(u32x4)(0u);
  }
  if (tid < 152) h16[tid] = 0;
  for (int q = tid; q < TB; q += 320) x_lds[q] = x[b*TB + q];
  float c = 0.f, hreg = 0.f;
  int jj = (tid < 300) ? tid : 0;
  const float* preB = pre + ((long long)dir*MTOT + (long long)b*TB)*G4;
  float* hb = hout + (long long)b*TB*HID + dir*HHALF + tid;
  const u32x4* hp = (const u32x4*)h16;
  int t0 = dir ? (TB-1) : 0;
  float pv0_c = preB[(long long)t0*G4 + jj];
  float pv1_c = preB[(long long)t0*G4 + jj + 300];
  bar_lds();
  #pragma unroll 1
  for (int s=0; s<TB; s++){
    int t = dir ? (TB-1-s) : s;
    int sn = (s+1 < TB) ? (s+1) : s;
    int tn = dir ? (TB-1-sn) : sn;
    float pv0_n = preB[(long long)tn*G4 + jj];
    float pv1_n = preB[(long long)tn*G4 + jj + 300];
    int xv = x_lds[t];
    if (xv > 0){
      if (tid < 300){
        float a0=0.f, b0=0.f, a1=0.f, b1=0.f;
        DOTQ(0,  w0_0,0, w1_0,0) DOTQ(1,  w0_0,4, w1_0,4)
        DOTQ(2,  w0_1,0, w1_1,0) DOTQ(3,  w0_1,4, w1_1,4)
        DOTQ(4,  w0_2,0, w1_2,0) DOTQ(5,  w0_2,4, w1_2,4)
        DOTQ(6,  w0_3,0, w1_3,0) DOTQ(7,  w0_3,4, w1_3,4)
        DOTQ(8,  w0_4,0, w1_4,0) DOTQ(9,  w0_4,4, w1_4,4)
        DOTQ(10, w0_5,0, w1_5,0) DOTQ(11, w0_5,4, w1_5,4)
        DOTQ(12, w0_6,0, w1_6,0) DOTQ(13, w0_6,4, w1_6,4)
        DOTQ(14, w0_7,0, w1_7,0) DOTQ(15, w0_7,4, w1_7,4)
        DOTQ(16, w0_8,0, w1_8,0) DOTQ(17, w0_8,4, w1_8,4)
        DOTQ(18, w0_9,0, w1_9,0)
        g_lds[tid]       = pv0_c + (a0 + b0);
        g_lds[tid + 300] = pv1_c + (a1 + b1);
      }
      bar_lds();
      if (tid < HHALF){
        float ig = g_lds[tid], fg = g_lds[HHALF+tid], gg = g_lds[2*HHALF+tid], og = g_lds[3*HHALF+tid];
        float cn = fsig(fg)*c + fsig(ig)*ftanh(gg);
        float hn = fsig(og)*ftanh(cn);
        _Float16 hh = (_Float16)hn;
        unsigned short hu; __builtin_memcpy(&hu, &hh, 2);
        h16[tid] = hu;
        c = cn; hreg = hn;
        hb[(long long)t*HID] = hn;
      }
      bar_lds();
    } else {
      if (tid < HHALF) hb[(long long)t*HID] = hreg;
    }
    pv0_c = pv0_n; pv1_c = pv1_n;
  }
}

// ---- emissions via MFMA: emis = (Abf(h2) @ Wout^T + bout) * mask ----
// M=32768, N=16 (one 16-wide tile), K=320. 256 blocks x 4 waves x 128 rows.
__global__ __launch_bounds__(256) void k_emis_mfma(const unsigned short* __restrict__ A,
                                                   const unsigned short* __restrict__ Wb,
                                                   const float* __restrict__ bsumo,
                                                   const int* __restrict__ x,
                                                   float* __restrict__ emis){
  int m0 = blockIdx.x * 128;
  int wid = threadIdx.x >> 6, lane = threadIdx.x & 63;
  int la = lane & 15, lk = lane >> 4;
  int mw = m0 + wid*32;
  f32x4 acc0, acc1;
  acc0[0]=0.f;acc0[1]=0.f;acc0[2]=0.f;acc0[3]=0.f;
  acc1[0]=0.f;acc1[1]=0.f;acc1[2]=0.f;acc1[3]=0.f;
  const unsigned short* Ap = A  + (long long)(mw + la)*KP + lk*8;
  const unsigned short* Bp = Wb + (long long)la*KP + lk*8;
  #pragma unroll 2
  for (int kk=0; kk<KP; kk+=32){
    short8 a0 = *(const short8*)(Ap + kk);
    short8 a1 = *(const short8*)(Ap + 16*KP + kk);
    short8 b0 = *(const short8*)(Bp + kk);
    acc0 = __builtin_amdgcn_mfma_f32_16x16x32_bf16(a0,b0,acc0,0,0,0);
    acc1 = __builtin_amdgcn_mfma_f32_16x16x32_bf16(a1,b0,acc1,0,0,0);
  }
  float bs = bsumo[la];
  #pragma unroll
  for (int r=0;r<4;r++){
    int row0 = mw + lk*4 + r;
    int row1 = row0 + 16;
    float m0v = (x[row0] > 0) ? 1.f : 0.f;
    float m1v = (x[row1] > 0) ? 1.f : 0.f;
    emis[(long long)row0*NTAG + la] = (acc0[r] + bs) * m0v;
    emis[(long long)row1*NTAG + la] = (acc1[r] + bs) * m1v;
  }
}

// ---- CRF partition: one wave per batch, alpha fully in registers ----
__global__ __launch_bounds__(64) void k_crf_part(const float* __restrict__ emis,
                                                 const float* __restrict__ trans,
                                                 const int* __restrict__ x,
                                                 float* __restrict__ out){
  int b = blockIdx.x;
  int lane = threadIdx.x;
  int i = lane & 15, q = lane >> 4;
  float t0 = trans[i*16 + q*4 + 0];
  float t1 = trans[i*16 + q*4 + 1];
  float t2 = trans[i*16 + q*4 + 2];
  float t3 = trans[i*16 + q*4 + 3];
  float al = (i == 14) ? 0.f : NEGV;
  const float* eb = emis + (long long)b*TB*NTAG + i;
  const int* xb = x + b*TB;
  float ht_n = eb[0];
  int   xv_n = xb[0];
  #pragma unroll 1
  for (int t=0; t<TB; t++){
    float ht = ht_n; int xv = xv_n;
    if (t+1 < TB){ ht_n = eb[(t+1)*NTAG]; xv_n = xb[t+1]; }
    if (xv > 0){
      float a0 = __shfl(al, q*4+0);
      float a1 = __shfl(al, q*4+1);
      float a2 = __shfl(al, q*4+2);
      float a3 = __shfl(al, q*4+3);
      float v0 = a0+t0, v1 = a1+t1, v2 = a2+t2, v3 = a3+t3;
      float mx = fmaxf(fmaxf(v0,v1), fmaxf(v2,v3));
      mx = fmaxf(mx, __shfl_xor(mx, 16));
      mx = fmaxf(mx, __shfl_xor(mx, 32));
      float sm = __expf(v0-mx) + __expf(v1-mx) + __expf(v2-mx) + __expf(v3-mx);
      sm += __shfl_xor(sm, 16);
      sm += __shfl_xor(sm, 32);
      al = mx + __logf(sm) + ht;
    }
  }
  float av = (lane < 16) ? (al + trans[15*16 + lane]) : -3.0e38f;
  float mx = av;
  mx = fmaxf(mx, __shfl_xor(mx, 1));
  mx = fmaxf(mx, __shfl_xor(mx, 2));
  mx = fmaxf(mx, __shfl_xor(mx, 4));
  mx = fmaxf(mx, __shfl_xor(mx, 8));
  float sm = (lane < 16) ? __expf(av - mx) : 0.f;
  sm += __shfl_xor(sm, 1);
  sm += __shfl_xor(sm, 2);
  sm += __shfl_xor(sm, 4);
  sm += __shfl_xor(sm, 8);
  if (lane == 0) out[b] = mx + __logf(sm);
}

// ---- CRF gold score: out[b] -= score ----
__global__ __launch_bounds__(64) void k_crf_score(const float* __restrict__ emis,
                                                  const float* __restrict__ trans,
                                                  const int* __restrict__ x,
                                                  const int* __restrict__ y,
                                                  float* __restrict__ out){
  int b = blockIdx.x;
  int lane = threadIdx.x;
  float part = 0.f; int cnt = 0;
  for (int t = lane; t < TB; t += 64){
    if (x[b*TB + t] > 0){
      int yt = y[b*TB + t];
      int prev = (t == 0) ? 14 : y[b*TB + t - 1];
      part += emis[((long long)b*TB + t)*NTAG + yt] + trans[yt*16 + prev];
      cnt++;
    }
  }
  #pragma unroll
  for (int d=1; d<64; d<<=1){ part += __shfl_xor(part, d); cnt += __shfl_xor(cnt, d); }
  if (lane == 0){
    int last = (cnt == 0) ? 14 : y[b*TB + cnt - 1];
    out[b] -= (part + trans[15*16 + last]);
  }
}

extern "C" void kernel_launch(void* const* d_in, const int* in_sizes, int n_in,
                              void* d_out, int out_size, void* d_ws, size_t ws_size,
                              hipStream_t stream){
  const int*   x     = (const int*)d_in[0];
  const int*   y     = (const int*)d_in[1];
  const float* emb   = (const float*)d_in[2];
  const float* Wih0  = (const float*)d_in[3];
  const float* Whh0  = (const float*)d_in[4];
  const float* bih0  = (const float*)d_in[5];
  const float* bhh0  = (const float*)d_in[6];
  const float* Wih1  = (const float*)d_in[7];
  const float* Whh1  = (const float*)d_in[8];
  const float* bih1  = (const float*)d_in[9];
  const float* bhh1  = (const float*)d_in[10];
  const float* Wout  = (const float*)d_in[11];
  const float* bout  = (const float*)d_in[12];
  const float* trans = (const float*)d_in[13];
  float* out = (float*)d_out;

  char* ws = (char*)d_ws;
  size_t off = 0;
  auto alloc = [&](size_t n){ char* p = ws + off; off = (off + n + 255) & ~(size_t)255; return p; };
  unsigned short* Abf  = (unsigned short*)alloc((size_t)MTOT*KP*2);
  unsigned short* Wbf0 = (unsigned short*)alloc((size_t)1216*KP*2);
  unsigned short* Wbf1 = (unsigned short*)alloc((size_t)1216*KP*2);
  unsigned short* Wobf = (unsigned short*)alloc((size_t)64*KP*2);
  float* bsum0 = (float*)alloc(1216*4);
  float* bsum1 = (float*)alloc(1216*4);
  float* bsumo = (float*)alloc(64*4);
  float* pre   = (float*)alloc((size_t)2*MTOT*G4*4);
  float* h1    = (float*)alloc((size_t)MTOT*HID*4);
  float* h2    = (float*)alloc((size_t)MTOT*HID*4);
  float* emis  = (float*)alloc((size_t)MTOT*NTAG*4);

  hipLaunchKernelGGL(k_cvt_w, dim3(1520), dim3(256), 0, stream, Wih0, bih0, bhh0, Wbf0, bsum0);
  hipLaunchKernelGGL(k_cvt_w, dim3(1520), dim3(256), 0, stream, Wih1, bih1, bhh1, Wbf1, bsum1);
  hipLaunchKernelGGL(k_cvt_wo, dim3(80), dim3(256), 0, stream, Wout, bout, Wobf, bsumo);
  hipLaunchKernelGGL(k_gather_embed, dim3(4096), dim3(256), 0, stream, x, emb, Abf);
  hipLaunchKernelGGL(k_proj, dim3(256,19), dim3(256), 0, stream, Abf, Wbf0, bsum0, pre);
  hipLaunchKernelGGL(k_rec, dim3(128), dim3(320), 0, stream, pre, Whh0, x, h1);
  hipLaunchKernelGGL(k_cvt_h, dim3(4096), dim3(256), 0, stream, h1, Abf);
  hipLaunchKernelGGL(k_proj, dim3(256,19), dim3(256), 0, stream, Abf, Wbf1, bsum1, pre);
  hipLaunchKernelGGL(k_rec, dim3(128), dim3(320), 0, stream, pre, Whh1, x, h2);
  hipLaunchKernelGGL(k_cvt_h, dim3(4096), dim3(256), 0, stream, h2, Abf);
  hipLaunchKernelGGL(k_emis_mfma, dim3(256), dim3(256), 0, stream, Abf, Wobf, bsumo, x, emis);
  hipLaunchKernelGGL(k_crf_part, dim3(64), dim3(64), 0, stream, emis, trans, x, out);
  hipLaunchKernelGGL(k_crf_score, dim3(64), dim3(64), 0, stream, emis, trans, x, y, out);
}

// Round 10
// 1731.343 us; speedup vs baseline: 1.1029x; 1.0032x over previous
//
#include <hip/hip_runtime.h>
#include <hip/hip_bf16.h>

#define TB 512
#define NB 64
#define HID 300
#define HHALF 150
#define G4 600
#define KP 320
#define MTOT (NB*TB)
#define NTAG 16
#define NEGV -10000.0f

using short8 = __attribute__((ext_vector_type(8))) short;
using f32x4  = __attribute__((ext_vector_type(4))) float;
using u32x8  = __attribute__((ext_vector_type(8))) unsigned;
using u32x4  = __attribute__((ext_vector_type(4))) unsigned;
using half2v = __attribute__((ext_vector_type(2))) _Float16;

__device__ __forceinline__ unsigned short f2bf(float f){
  union { float f; unsigned u; } v; v.f = f;
  unsigned r = v.u + 0x7FFFu + ((v.u >> 16) & 1u);
  return (unsigned short)(r >> 16);
}
__device__ __forceinline__ float bf2f(unsigned short u){
  union { unsigned u; float f; } v; v.u = ((unsigned)u) << 16; return v.f;
}
__device__ __forceinline__ float fsig(float x){ return __fdividef(1.f, 1.f + __expf(-x)); }
__device__ __forceinline__ float ftanh(float x){ return 1.f - __fdividef(2.f, __expf(2.f*x) + 1.f); }

__device__ __forceinline__ unsigned pkh(float a, float b){
  _Float16 ha = (_Float16)a, hb = (_Float16)b;
  unsigned short ua, ub;
  __builtin_memcpy(&ua, &ha, 2); __builtin_memcpy(&ub, &hb, 2);
  return (unsigned)ua | ((unsigned)ub << 16);
}
__device__ __forceinline__ float dot2(unsigned w, unsigned h, float acc){
  half2v wv, hv;
  __builtin_memcpy(&wv, &w, 4); __builtin_memcpy(&hv, &h, 4);
  return __builtin_amdgcn_fdot2(wv, hv, acc, false);
}

// raw workgroup barrier: order LDS only, leave vmcnt in flight
__device__ __forceinline__ void bar_lds(){
  asm volatile("s_waitcnt lgkmcnt(0)" ::: "memory");
  __builtin_amdgcn_s_barrier();
  asm volatile("" ::: "memory");
}

// ---- staging / conversion kernels ----
__global__ void k_gather_embed(const int* __restrict__ x, const float* __restrict__ emb,
                               unsigned short* __restrict__ Abf){
  long long total = (long long)MTOT * KP;
  for (long long idx = (long long)blockIdx.x*blockDim.x + threadIdx.x; idx < total;
       idx += (long long)gridDim.x*blockDim.x){
    int m = (int)(idx / KP), k = (int)(idx % KP);
    float v = 0.f;
    if (k < HID) v = emb[(long long)x[m]*HID + k];
    Abf[idx] = f2bf(v);
  }
}

// zero cols 300..319 of a 32768x320 bf16 panel (run every launch: ws re-poisoned)
__global__ void k_padzero(unsigned short* __restrict__ P){
  int idx = blockIdx.x*blockDim.x + threadIdx.x;
  if (idx >= MTOT*20) return;
  int m = idx / 20, k = 300 + idx % 20;
  P[(long long)m*KP + k] = 0;
}

__global__ void k_cvt_w(const float* __restrict__ Wih, const float* __restrict__ bih,
                        const float* __restrict__ bhh,
                        unsigned short* __restrict__ Wbf, float* __restrict__ bsum){
  int idx = blockIdx.x*blockDim.x + threadIdx.x;
  if (idx >= 1216*KP) return;
  int n = idx / KP, k = idx % KP;
  float v = (n < 1200 && k < HID) ? Wih[(long long)n*HID + k] : 0.f;
  Wbf[idx] = f2bf(v);
  if (k == 0) bsum[n] = (n < 1200) ? (bih[n] + bhh[n]) : 0.f;
}

// Wout (16x300) -> padded bf16 panel (64x320) + bias
__global__ void k_cvt_wo(const float* __restrict__ Wout, const float* __restrict__ bout,
                         unsigned short* __restrict__ Wobf, float* __restrict__ bsumo){
  int idx = blockIdx.x*blockDim.x + threadIdx.x;
  if (idx >= 64*KP) return;
  int n = idx / KP, k = idx % KP;
  float v = (n < NTAG && k < HID) ? Wout[n*HID + k] : 0.f;
  Wobf[idx] = f2bf(v);
  if (k == 0) bsumo[n] = (n < NTAG) ? bout[n] : 0.f;
}

// ---- bf16 MFMA projection GEMM: preb[dir][m][j] = bf16(A(m,k) @ W(n,k)^T + bsum) ----
__global__ __launch_bounds__(256) void k_proj(const unsigned short* __restrict__ A,
                                              const unsigned short* __restrict__ Wb,
                                              const float* __restrict__ bsum,
                                              unsigned short* __restrict__ preb){
  int m0 = blockIdx.x * 128;
  int n0 = blockIdx.y * 64;
  int wid = threadIdx.x >> 6, lane = threadIdx.x & 63;
  int la = lane & 15, lk = lane >> 4;
  int mw = m0 + wid*32;
  f32x4 acc[2][4];
  #pragma unroll
  for (int i=0;i<2;i++){
    #pragma unroll
    for (int j=0;j<4;j++){ acc[i][j][0]=0.f; acc[i][j][1]=0.f; acc[i][j][2]=0.f; acc[i][j][3]=0.f; }
  }
  const unsigned short* Ap = A  + (long long)(mw + la)*KP + lk*8;
  const unsigned short* Bp = Wb + (long long)(n0 + la)*KP + lk*8;
  #pragma unroll 2
  for (int kk=0; kk<KP; kk+=32){
    short8 a0 = *(const short8*)(Ap + kk);
    short8 a1 = *(const short8*)(Ap + 16*KP + kk);
    short8 b0 = *(const short8*)(Bp + kk);
    short8 b1 = *(const short8*)(Bp + 16*KP + kk);
    short8 b2 = *(const short8*)(Bp + 32*KP + kk);
    short8 b3 = *(const short8*)(Bp + 48*KP + kk);
    acc[0][0] = __builtin_amdgcn_mfma_f32_16x16x32_bf16(a0,b0,acc[0][0],0,0,0);
    acc[0][1] = __builtin_amdgcn_mfma_f32_16x16x32_bf16(a0,b1,acc[0][1],0,0,0);
    acc[0][2] = __builtin_amdgcn_mfma_f32_16x16x32_bf16(a0,b2,acc[0][2],0,0,0);
    acc[0][3] = __builtin_amdgcn_mfma_f32_16x16x32_bf16(a0,b3,acc[0][3],0,0,0);
    acc[1][0] = __builtin_amdgcn_mfma_f32_16x16x32_bf16(a1,b0,acc[1][0],0,0,0);
    acc[1][1] = __builtin_amdgcn_mfma_f32_16x16x32_bf16(a1,b1,acc[1][1],0,0,0);
    acc[1][2] = __builtin_amdgcn_mfma_f32_16x16x32_bf16(a1,b2,acc[1][2],0,0,0);
    acc[1][3] = __builtin_amdgcn_mfma_f32_16x16x32_bf16(a1,b3,acc[1][3],0,0,0);
  }
  #pragma unroll
  for (int ms=0; ms<2; ms++){
    #pragma unroll
    for (int ns=0; ns<4; ns++){
      int n = n0 + ns*16 + la;
      if (n < 1200){
        int dir = (n >= 600) ? 1 : 0;
        int j = n - dir*600;
        float bs = bsum[n];
        #pragma unroll
        for (int r=0;r<4;r++){
          int row = mw + ms*16 + lk*4 + r;
          preb[((long long)dir*MTOT + row)*G4 + j] = f2bf(acc[ms][ns][r] + bs);
        }
      }
    }
  }
}

// ---- LSTM recurrence (R7 structure + bf16 pre, depth-2 prefetch, bf16 h out) ----
// 320 threads (5 waves). Thread j<300 owns gate rows j and j+300; weights
// register-resident as packed-f16 named ext-vectors. h broadcast via LDS f16.
// pre is bf16 (half the stream bytes); prefetch runs 2 steps ahead so masked-step
// bursts don't drain the in-flight window. h written directly as bf16 into the
// next GEMM's A-panel (k_cvt_h deleted; no f32 h buffer).
#define MK8(P,B) (u32x8){ pkh(P[(B)],P[(B)+1]), pkh(P[(B)+2],P[(B)+3]), \
  pkh(P[(B)+4],P[(B)+5]), pkh(P[(B)+6],P[(B)+7]), pkh(P[(B)+8],P[(B)+9]), \
  pkh(P[(B)+10],P[(B)+11]), pkh(P[(B)+12],P[(B)+13]), pkh(P[(B)+14],P[(B)+15]) }
#define MK4T(P) (u32x4){ pkh(P[144],P[145]), pkh(P[146],P[147]), pkh(P[148],P[149]), 0u }
#define DOTQ(hq, W0, E0, W1, E1) { u32x4 hv = hp[(hq)]; \
  a0 = dot2(W0[(E0)+0], hv.x, a0); b0 = dot2(W0[(E0)+1], hv.y, b0); \
  a0 = dot2(W0[(E0)+2], hv.z, a0); b0 = dot2(W0[(E0)+3], hv.w, b0); \
  a1 = dot2(W1[(E1)+0], hv.x, a1); b1 = dot2(W1[(E1)+1], hv.y, b1); \
  a1 = dot2(W1[(E1)+2], hv.z, a1); b1 = dot2(W1[(E1)+3], hv.w, b1); }

__global__ __launch_bounds__(320, 1) void k_rec(const unsigned short* __restrict__ preb,
                                                const float* __restrict__ Whh,
                                                const int* __restrict__ x,
                                                unsigned short* __restrict__ hpan){
  int dir = blockIdx.x >> 6;
  int b   = blockIdx.x & 63;
  int tid = threadIdx.x;
  __shared__ __align__(16) unsigned short h16[152];
  __shared__ float g_lds[G4];
  __shared__ int   x_lds[TB];
  const float* wr0 = Whh + (long long)(dir*G4 + tid)*HHALF;
  const float* wr1 = wr0 + 300*HHALF;
  u32x8 w0_0,w0_1,w0_2,w0_3,w0_4,w0_5,w0_6,w0_7,w0_8;
  u32x8 w1_0,w1_1,w1_2,w1_3,w1_4,w1_5,w1_6,w1_7,w1_8;
  u32x4 w0_9, w1_9;
  if (tid < 300){
    w0_0=MK8(wr0,0);   w0_1=MK8(wr0,16);  w0_2=MK8(wr0,32);  w0_3=MK8(wr0,48);
    w0_4=MK8(wr0,64);  w0_5=MK8(wr0,80);  w0_6=MK8(wr0,96);  w0_7=MK8(wr0,112);
    w0_8=MK8(wr0,128); w0_9=MK4T(wr0);
    w1_0=MK8(wr1,0);   w1_1=MK8(wr1,16);  w1_2=MK8(wr1,32);  w1_3=MK8(wr1,48);
    w1_4=MK8(wr1,64);  w1_5=MK8(wr1,80);  w1_6=MK8(wr1,96);  w1_7=MK8(wr1,112);
    w1_8=MK8(wr1,128); w1_9=MK4T(wr1);
  } else {
    w0_0=(u32x8)(0u);w0_1=(u32x8)(0u);w0_2=(u32x8)(0u);w0_3=(u32x8)(0u);
    w0_4=(u32x8)(0u);w0_5=(u32x8)(0u);w0_6=(u32x8)(0u);w0_7=(u32x8)(0u);
    w0_8=(u32x8)(0u);w0_9=(u32x4)(0u);
    w1_0=(u32x8)(0u);w1_1=(u32x8)(0u);w1_2=(u32x8)(0u);w1_3=(u32x8)(0u);
    w1_4=(u32x8)(0u);w1_5=(u32x8)(0u);w1_6=(u32x8)(0u);w1_7=(u32x8)(0u);
    w1_8=(u32x8)(0u);w1_9=(u32x4)(0u);
  }
  if (tid < 152) h16[tid] = 0;
  for (int q = tid; q < TB; q += 320) x_lds[q] = x[b*TB + q];
  float c = 0.f;
  unsigned short hu_reg = 0;
  int jj = (tid < 300) ? tid : 0;
  const unsigned short* preB = preb + ((long long)dir*MTOT + (long long)b*TB)*G4;
  unsigned short* hb = hpan + ((long long)b*TB)*KP + dir*HHALF + tid;
  const u32x4* hp = (const u32x4*)h16;
  // depth-2 rolling prefetch of pre (bf16)
  int tA = dir ? (TB-1) : 0;
  int tBt = dir ? (TB-2) : 1;
  unsigned short q0_a = preB[(long long)tA*G4 + jj];
  unsigned short q1_a = preB[(long long)tA*G4 + jj + 300];
  unsigned short q0_b = preB[(long long)tBt*G4 + jj];
  unsigned short q1_b = preB[(long long)tBt*G4 + jj + 300];
  bar_lds();
  #pragma unroll 1
  for (int s=0; s<TB; s++){
    int t = dir ? (TB-1-s) : s;
    int sn = (s+2 < TB) ? (s+2) : s;       // prefetch 2 ahead (clamped)
    int tn = dir ? (TB-1-sn) : sn;
    unsigned short q0_c = preB[(long long)tn*G4 + jj];
    unsigned short q1_c = preB[(long long)tn*G4 + jj + 300];
    int xv = x_lds[t];
    if (xv > 0){
      if (tid < 300){
        float a0=0.f, b0=0.f, a1=0.f, b1=0.f;
        DOTQ(0,  w0_0,0, w1_0,0) DOTQ(1,  w0_0,4, w1_0,4)
        DOTQ(2,  w0_1,0, w1_1,0) DOTQ(3,  w0_1,4, w1_1,4)
        DOTQ(4,  w0_2,0, w1_2,0) DOTQ(5,  w0_2,4, w1_2,4)
        DOTQ(6,  w0_3,0, w1_3,0) DOTQ(7,  w0_3,4, w1_3,4)
        DOTQ(8,  w0_4,0, w1_4,0) DOTQ(9,  w0_4,4, w1_4,4)
        DOTQ(10, w0_5,0, w1_5,0) DOTQ(11, w0_5,4, w1_5,4)
        DOTQ(12, w0_6,0, w1_6,0) DOTQ(13, w0_6,4, w1_6,4)
        DOTQ(14, w0_7,0, w1_7,0) DOTQ(15, w0_7,4, w1_7,4)
        DOTQ(16, w0_8,0, w1_8,0) DOTQ(17, w0_8,4, w1_8,4)
        DOTQ(18, w0_9,0, w1_9,0)
        g_lds[tid]       = bf2f(q0_a) + (a0 + b0);
        g_lds[tid + 300] = bf2f(q1_a) + (a1 + b1);
      }
      bar_lds();
      if (tid < HHALF){
        float ig = g_lds[tid], fg = g_lds[HHALF+tid], gg = g_lds[2*HHALF+tid], og = g_lds[3*HHALF+tid];
        float cn = fsig(fg)*c + fsig(ig)*ftanh(gg);
        float hn = fsig(og)*ftanh(cn);
        _Float16 hh = (_Float16)hn;
        unsigned short hu; __builtin_memcpy(&hu, &hh, 2);
        h16[tid] = hu;
        c = cn;
        hu_reg = f2bf(hn);
        hb[(long long)t*KP] = hu_reg;
      }
      bar_lds();
    } else {
      if (tid < HHALF) hb[(long long)t*KP] = hu_reg;
    }
    q0_a = q0_b; q1_a = q1_b;
    q0_b = q0_c; q1_b = q1_c;
  }
}

// ---- emissions via MFMA: emis = (Abf(h2) @ Wout^T + bout) * mask ----
__global__ __launch_bounds__(256) void k_emis_mfma(const unsigned short* __restrict__ A,
                                                   const unsigned short* __restrict__ Wb,
                                                   const float* __restrict__ bsumo,
                                                   const int* __restrict__ x,
                                                   float* __restrict__ emis){
  int m0 = blockIdx.x * 128;
  int wid = threadIdx.x >> 6, lane = threadIdx.x & 63;
  int la = lane & 15, lk = lane >> 4;
  int mw = m0 + wid*32;
  f32x4 acc0, acc1;
  acc0[0]=0.f;acc0[1]=0.f;acc0[2]=0.f;acc0[3]=0.f;
  acc1[0]=0.f;acc1[1]=0.f;acc1[2]=0.f;acc1[3]=0.f;
  const unsigned short* Ap = A  + (long long)(mw + la)*KP + lk*8;
  const unsigned short* Bp = Wb + (long long)la*KP + lk*8;
  #pragma unroll 2
  for (int kk=0; kk<KP; kk+=32){
    short8 a0 = *(const short8*)(Ap + kk);
    short8 a1 = *(const short8*)(Ap + 16*KP + kk);
    short8 b0 = *(const short8*)(Bp + kk);
    acc0 = __builtin_amdgcn_mfma_f32_16x16x32_bf16(a0,b0,acc0,0,0,0);
    acc1 = __builtin_amdgcn_mfma_f32_16x16x32_bf16(a1,b0,acc1,0,0,0);
  }
  float bs = bsumo[la];
  #pragma unroll
  for (int r=0;r<4;r++){
    int row0 = mw + lk*4 + r;
    int row1 = row0 + 16;
    float m0v = (x[row0] > 0) ? 1.f : 0.f;
    float m1v = (x[row1] > 0) ? 1.f : 0.f;
    emis[(long long)row0*NTAG + la] = (acc0[r] + bs) * m0v;
    emis[(long long)row1*NTAG + la] = (acc1[r] + bs) * m1v;
  }
}

// ---- CRF partition: one wave per batch, alpha fully in registers ----
__global__ __launch_bounds__(64) void k_crf_part(const float* __restrict__ emis,
                                                 const float* __restrict__ trans,
                                                 const int* __restrict__ x,
                                                 float* __restrict__ out){
  int b = blockIdx.x;
  int lane = threadIdx.x;
  int i = lane & 15, q = lane >> 4;
  float t0 = trans[i*16 + q*4 + 0];
  float t1 = trans[i*16 + q*4 + 1];
  float t2 = trans[i*16 + q*4 + 2];
  float t3 = trans[i*16 + q*4 + 3];
  float al = (i == 14) ? 0.f : NEGV;
  const float* eb = emis + (long long)b*TB*NTAG + i;
  const int* xb = x + b*TB;
  float ht_n = eb[0];
  int   xv_n = xb[0];
  #pragma unroll 1
  for (int t=0; t<TB; t++){
    float ht = ht_n; int xv = xv_n;
    if (t+1 < TB){ ht_n = eb[(t+1)*NTAG]; xv_n = xb[t+1]; }
    if (xv > 0){
      float a0 = __shfl(al, q*4+0);
      float a1 = __shfl(al, q*4+1);
      float a2 = __shfl(al, q*4+2);
      float a3 = __shfl(al, q*4+3);
      float v0 = a0+t0, v1 = a1+t1, v2 = a2+t2, v3 = a3+t3;
      float mx = fmaxf(fmaxf(v0,v1), fmaxf(v2,v3));
      mx = fmaxf(mx, __shfl_xor(mx, 16));
      mx = fmaxf(mx, __shfl_xor(mx, 32));
      float sm = __expf(v0-mx) + __expf(v1-mx) + __expf(v2-mx) + __expf(v3-mx);
      sm += __shfl_xor(sm, 16);
      sm += __shfl_xor(sm, 32);
      al = mx + __logf(sm) + ht;
    }
  }
  float av = (lane < 16) ? (al + trans[15*16 + lane]) : -3.0e38f;
  float mx = av;
  mx = fmaxf(mx, __shfl_xor(mx, 1));
  mx = fmaxf(mx, __shfl_xor(mx, 2));
  mx = fmaxf(mx, __shfl_xor(mx, 4));
  mx = fmaxf(mx, __shfl_xor(mx, 8));
  float sm = (lane < 16) ? __expf(av - mx) : 0.f;
  sm += __shfl_xor(sm, 1);
  sm += __shfl_xor(sm, 2);
  sm += __shfl_xor(sm, 4);
  sm += __shfl_xor(sm, 8);
  if (lane == 0) out[b] = mx + __logf(sm);
}

// ---- CRF gold score: out[b] -= score ----
__global__ __launch_bounds__(64) void k_crf_score(const float* __restrict__ emis,
                                                  const float* __restrict__ trans,
                                                  const int* __restrict__ x,
                                                  const int* __restrict__ y,
                                                  float* __restrict__ out){
  int b = blockIdx.x;
  int lane = threadIdx.x;
  float part = 0.f; int cnt = 0;
  for (int t = lane; t < TB; t += 64){
    if (x[b*TB + t] > 0){
      int yt = y[b*TB + t];
      int prev = (t == 0) ? 14 : y[b*TB + t - 1];
      part += emis[((long long)b*TB + t)*NTAG + yt] + trans[yt*16 + prev];
      cnt++;
    }
  }
  #pragma unroll
  for (int d=1; d<64; d<<=1){ part += __shfl_xor(part, d); cnt += __shfl_xor(cnt, d); }
  if (lane == 0){
    int last = (cnt == 0) ? 14 : y[b*TB + cnt - 1];
    out[b] -= (part + trans[15*16 + last]);
  }
}

extern "C" void kernel_launch(void* const* d_in, const int* in_sizes, int n_in,
                              void* d_out, int out_size, void* d_ws, size_t ws_size,
                              hipStream_t stream){
  const int*   x     = (const int*)d_in[0];
  const int*   y     = (const int*)d_in[1];
  const float* emb   = (const float*)d_in[2];
  const float* Wih0  = (const float*)d_in[3];
  const float* Whh0  = (const float*)d_in[4];
  const float* bih0  = (const float*)d_in[5];
  const float* bhh0  = (const float*)d_in[6];
  const float* Wih1  = (const float*)d_in[7];
  const float* Whh1  = (const float*)d_in[8];
  const float* bih1  = (const float*)d_in[9];
  const float* bhh1  = (const float*)d_in[10];
  const float* Wout  = (const float*)d_in[11];
  const float* bout  = (const float*)d_in[12];
  const float* trans = (const float*)d_in[13];
  float* out = (float*)d_out;

  char* ws = (char*)d_ws;
  size_t off = 0;
  auto alloc = [&](size_t n){ char* p = ws + off; off = (off + n + 255) & ~(size_t)255; return p; };
  unsigned short* Abf  = (unsigned short*)alloc((size_t)MTOT*KP*2);   // embed / h2 panel
  unsigned short* Ah1  = (unsigned short*)alloc((size_t)MTOT*KP*2);   // h1 panel
  unsigned short* Wbf0 = (unsigned short*)alloc((size_t)1216*KP*2);
  unsigned short* Wbf1 = (unsigned short*)alloc((size_t)1216*KP*2);
  unsigned short* Wobf = (unsigned short*)alloc((size_t)64*KP*2);
  float* bsum0 = (float*)alloc(1216*4);
  float* bsum1 = (float*)alloc(1216*4);
  float* bsumo = (float*)alloc(64*4);
  unsigned short* preb = (unsigned short*)alloc((size_t)2*MTOT*G4*2);
  float* emis  = (float*)alloc((size_t)MTOT*NTAG*4);

  hipLaunchKernelGGL(k_cvt_w, dim3(1520), dim3(256), 0, stream, Wih0, bih0, bhh0, Wbf0, bsum0);
  hipLaunchKernelGGL(k_cvt_w, dim3(1520), dim3(256), 0, stream, Wih1, bih1, bhh1, Wbf1, bsum1);
  hipLaunchKernelGGL(k_cvt_wo, dim3(80), dim3(256), 0, stream, Wout, bout, Wobf, bsumo);
  hipLaunchKernelGGL(k_gather_embed, dim3(4096), dim3(256), 0, stream, x, emb, Abf);
  hipLaunchKernelGGL(k_padzero, dim3(2560), dim3(256), 0, stream, Ah1);
  hipLaunchKernelGGL(k_proj, dim3(256,19), dim3(256), 0, stream, Abf, Wbf0, bsum0, preb);
  hipLaunchKernelGGL(k_rec, dim3(128), dim3(320), 0, stream, preb, Whh0, x, Ah1);
  hipLaunchKernelGGL(k_proj, dim3(256,19), dim3(256), 0, stream, Ah1, Wbf1, bsum1, preb);
  hipLaunchKernelGGL(k_rec, dim3(128), dim3(320), 0, stream, preb, Whh1, x, Abf);
  hipLaunchKernelGGL(k_emis_mfma, dim3(256), dim3(256), 0, stream, Abf, Wobf, bsumo, x, emis);
  hipLaunchKernelGGL(k_crf_part, dim3(64), dim3(64), 0, stream, emis, trans, x, out);
  hipLaunchKernelGGL(k_crf_score, dim3(64), dim3(64), 0, stream, emis, trans, x, y, out);
}